// Round 4
// baseline (440.748 us; speedup 1.0000x reference)
//
#include <hip/hip_runtime.h>

#define NBINS 512
#define BDIM 256
#define MAXHB 1024   // max histogram bins; actual HB = ceil(N/512) = 196

// ---------------------------------------------------------------------------
// Binning pipeline: sort the B*K gathers by neighbor row (bin = nn>>9) so the
// 205MB-footprint side is swept in ~1MB bands (DRAM/L3 locality); the base-row
// side (16.8MB footprint) becomes the random one but fits in L2+L3.
// ---------------------------------------------------------------------------

__global__ void init_hist(int* __restrict__ hist, int hb) {
    int t = blockIdx.x * blockDim.x + threadIdx.x;
    if (t < hb) hist[t] = 0;
}

__global__ __launch_bounds__(BDIM) void count_kernel(
        const float* __restrict__ y, int* __restrict__ hist,
        int items, int hb) {
    __shared__ int lh[MAXHB];
    for (int i = threadIdx.x; i < hb; i += BDIM) lh[i] = 0;
    __syncthreads();
    const int total = gridDim.x * BDIM;
    for (int i = blockIdx.x * BDIM + threadIdx.x; i < items; i += total) {
        int nn = (int)y[i];
        atomicAdd(&lh[nn >> 9], 1);
    }
    __syncthreads();
    for (int i = threadIdx.x; i < hb; i += BDIM)
        if (lh[i]) atomicAdd(&hist[i], lh[i]);
}

__global__ __launch_bounds__(MAXHB) void scan_kernel(
        const int* __restrict__ hist, int* __restrict__ cursor, int hb) {
    __shared__ int s[MAXHB];
    const int t = threadIdx.x;
    int v = (t < hb) ? hist[t] : 0;
    s[t] = v;
    __syncthreads();
    for (int off = 1; off < MAXHB; off <<= 1) {
        int x = (t >= off) ? s[t - off] : 0;
        __syncthreads();
        s[t] += x;
        __syncthreads();
    }
    if (t < hb) cursor[t] = s[t] - v;   // exclusive scan -> running cursor
}

__global__ __launch_bounds__(BDIM) void scatter_kernel(
        const float* __restrict__ y, int* __restrict__ cursor,
        uint2* __restrict__ itembuf, int items) {
    const int total = gridDim.x * BDIM;
    for (int i = blockIdx.x * BDIM + threadIdx.x; i < items; i += total) {
        int nn = (int)y[i];
        int pos = atomicAdd(&cursor[nn >> 9], 1);
        itembuf[pos] = make_uint2((unsigned)nn, (unsigned)i);
    }
}

// One block = 16 consecutive (bin-sorted) items; wave w handles 4 of them.
// Gathered rows are band-local (sequential-ish); base rows random in 16.8MB.
__global__ __launch_bounds__(BDIM) void gather_kernel(
        const float* __restrict__ outputs,
        const uint2* __restrict__ itembuf,
        float* __restrict__ add,        // (items) in ws, indexed by original idx
        int items, int K) {
    const int w    = threadIdx.x >> 6;
    const int lane = threadIdx.x & 63;
    const int ibase = blockIdx.x * 16 + w * 4;

    uint2 it[4];
    #pragma unroll
    for (int j = 0; j < 4; ++j)
        it[j] = itembuf[min(ibase + j, items - 1)];

    float4 g0[4], g1[4], c0[4], c1[4];
    #pragma unroll
    for (int j = 0; j < 4; ++j) {
        const float4* gp = (const float4*)(outputs + (size_t)it[j].x * NBINS);
        const unsigned b = it[j].y / (unsigned)K;
        const float4* bp = (const float4*)(outputs + (size_t)b * NBINS);
        g0[j] = gp[lane];
        g1[j] = gp[64 + lane];
        c0[j] = bp[lane];
        c1[j] = bp[64 + lane];
    }

    float m[4];
    #pragma unroll
    for (int j = 0; j < 4; ++j) {
        m[j] = fmaxf(fmaxf(fmaxf(g0[j].x + c0[j].x, g0[j].y + c0[j].y),
                           fmaxf(g0[j].z + c0[j].z, g0[j].w + c0[j].w)),
                     fmaxf(fmaxf(g1[j].x + c1[j].x, g1[j].y + c1[j].y),
                           fmaxf(g1[j].z + c1[j].z, g1[j].w + c1[j].w)));
    }

    #pragma unroll
    for (int off = 32; off > 0; off >>= 1) {
        #pragma unroll
        for (int j = 0; j < 4; ++j)
            m[j] = fmaxf(m[j], __shfl_down(m[j], off, 64));
    }

    if (lane == 0) {
        #pragma unroll
        for (int j = 0; j < 4; ++j)
            if (ibase + j < items) add[it[j].y] = m[j];
    }
}

// booster weights + weighted-add block partials; one thread per batch element.
__global__ __launch_bounds__(BDIM) void booster_kernel(
        const float* __restrict__ add,
        const float* __restrict__ weights,
        float* __restrict__ out,        // [cost, diff, bnorm, booster(B)]
        float* __restrict__ wpart,      // (B)
        int K) {
    const int b = blockIdx.x * BDIM + threadIdx.x;
    const float4* ap = (const float4*)(add + (size_t)b * K);
    float sum = 0.0f;
    for (int j = 0; j < K / 4; ++j) {
        float4 a = ap[j];
        sum += (a.x + a.y) + (a.z + a.w);
    }
    out[3 + b] = fmaxf(0.5f, (2.0f - sum / (float)K) * 0.5f);
    wpart[b] = weights[b] * sum;
}

__global__ __launch_bounds__(NBINS) void colsum_kernel(
        const float* __restrict__ outputs,
        float* __restrict__ part, int rows_per_block) {
    const int t = threadIdx.x;
    const size_t r0 = (size_t)blockIdx.x * rows_per_block;
    float local = 0.0f;
    for (int r = 0; r < rows_per_block; ++r)
        local += outputs[(r0 + r) * NBINS + t];
    part[(size_t)blockIdx.x * NBINS + t] = local;
}

__global__ __launch_bounds__(NBINS) void final_kernel(
        const float* __restrict__ part,
        const float* __restrict__ wpart,
        float* __restrict__ out,
        int npart, int B, float inv_count, float inv_target) {
    __shared__ float smax[NBINS];
    __shared__ float smin[NBINS];
    __shared__ float ssum[NBINS];
    const int t = threadIdx.x;

    float v = 0.0f;
    for (int j = 0; j < npart; ++j)
        v += part[(size_t)j * NBINS + t];
    smax[t] = v;
    smin[t] = v;

    float wsum = 0.0f;
    for (int i = t; i < B; i += NBINS)
        wsum += wpart[i];
    ssum[t] = wsum;
    __syncthreads();

    for (int s = NBINS / 2; s > 0; s >>= 1) {
        if (t < s) {
            smax[t] = fmaxf(smax[t], smax[t + s]);
            smin[t] = fminf(smin[t], smin[t + s]);
            ssum[t] += ssum[t + s];
        }
        __syncthreads();
    }
    if (t == 0) {
        float add_mean = ssum[0] * inv_count;
        float d = 2.0f - add_mean;
        float diff = d * d;
        float bn = (smax[0] - smin[0]) * inv_target;
        out[0] = bn + diff;
        out[1] = diff;
        out[2] = bn;
    }
}

extern "C" void kernel_launch(void* const* d_in, const int* in_sizes, int n_in,
                              void* d_out, int out_size, void* d_ws, size_t ws_size,
                              hipStream_t stream) {
    const float* outputs = (const float*)d_in[0];  // (N, 512)
    const float* y       = (const float*)d_in[1];  // (B, K)
    const float* weights = (const float*)d_in[2];  // (B,)
    float* out = (float*)d_out;

    const int B = in_sizes[2];              // 8192
    const int K = in_sizes[1] / B;          // 16
    const int N = in_sizes[0] / NBINS;      // 100000
    const int ITEMS = B * K;                // 131072
    const int HB = (N + 511) >> 9;          // 196 bins

    // ws layout: hist[MAXHB] cursor[MAXHB] (ints) | items[ITEMS] (uint2) |
    //            add[ITEMS] | wpart[B] | colpart[256*NBINS] (floats)
    char* wsb = (char*)d_ws;
    int*   hist    = (int*)wsb;
    int*   cursor  = hist + MAXHB;
    uint2* itembuf = (uint2*)(wsb + 2 * MAXHB * sizeof(int));
    float* add     = (float*)(itembuf + ITEMS);
    float* wpart   = add + ITEMS;
    float* colpart = wpart + B;

    const int COL_BLOCKS = 256;
    const int rows_per_block = B / COL_BLOCKS;

    init_hist<<<(HB + 255) / 256, 256, 0, stream>>>(hist, HB);
    count_kernel<<<128, BDIM, 0, stream>>>(y, hist, ITEMS, HB);
    scan_kernel<<<1, MAXHB, 0, stream>>>(hist, cursor, HB);
    scatter_kernel<<<128, BDIM, 0, stream>>>(y, cursor, itembuf, ITEMS);
    gather_kernel<<<(ITEMS + 15) / 16, BDIM, 0, stream>>>(outputs, itembuf, add, ITEMS, K);
    colsum_kernel<<<COL_BLOCKS, NBINS, 0, stream>>>(outputs, colpart, rows_per_block);
    booster_kernel<<<B / BDIM, BDIM, 0, stream>>>(add, weights, out, wpart, K);
    final_kernel<<<1, NBINS, 0, stream>>>(colpart, wpart, out,
                                          COL_BLOCKS, B,
                                          1.0f / (float)(B * K),
                                          (float)NBINS / (float)N);
}

// Round 5
// 346.140 us; speedup vs baseline: 1.2733x; 1.2733x over previous
//
#include <hip/hip_runtime.h>

#define NBINS 512
#define BDIM 256

// ---------------------------------------------------------------------------
// Kernel 1: gather + rowmax. One block per batch row b. Wave w (0..3) keeps
// the base row outputs[b,:] in registers (8 floats/lane, two contiguous 1KB
// segments) and processes neighbors k=4w..4w+3 (8 independent fully-coalesced
// float4 gather loads in flight per wave). Barrier-free; lane 0 of each wave
// writes its 4 results as one float4.
// ---------------------------------------------------------------------------
__global__ __launch_bounds__(BDIM) void gather_kernel(
        const float* __restrict__ outputs,
        const float* __restrict__ y,
        float* __restrict__ add,        // (B*K) in ws
        int K) {
    const int b    = blockIdx.x;
    const int w    = threadIdx.x >> 6;
    const int lane = threadIdx.x & 63;

    const int kbase = w * 4;
    int nn[4];
    #pragma unroll
    for (int j = 0; j < 4; ++j)
        nn[j] = (int)y[b * K + kbase + j];   // y >= 0 so trunc == int cast

    // Start the random-side loads first; base row after.
    float4 g0[4], g1[4];
    #pragma unroll
    for (int j = 0; j < 4; ++j) {
        const float4* gp = (const float4*)(outputs + (size_t)nn[j] * NBINS);
        g0[j] = gp[lane];
        g1[j] = gp[64 + lane];
    }

    const float4* bp = (const float4*)(outputs + (size_t)b * NBINS);
    const float4  b0 = bp[lane];
    const float4  b1 = bp[64 + lane];

    float m[4];
    #pragma unroll
    for (int j = 0; j < 4; ++j) {
        m[j] = fmaxf(fmaxf(fmaxf(g0[j].x + b0.x, g0[j].y + b0.y),
                           fmaxf(g0[j].z + b0.z, g0[j].w + b0.w)),
                     fmaxf(fmaxf(g1[j].x + b1.x, g1[j].y + b1.y),
                           fmaxf(g1[j].z + b1.z, g1[j].w + b1.w)));
    }

    #pragma unroll
    for (int off = 32; off > 0; off >>= 1) {
        #pragma unroll
        for (int j = 0; j < 4; ++j)
            m[j] = fmaxf(m[j], __shfl_down(m[j], off, 64));
    }

    if (lane == 0) {
        *((float4*)(add + (size_t)b * K + kbase)) =
            make_float4(m[0], m[1], m[2], m[3]);   // 16B-aligned (kbase%4==0)
    }
}

// ---------------------------------------------------------------------------
// Kernel 2: fused colsum + booster (independent work, branch on blockIdx).
// Blocks [0, COL_BLOCKS): per-column partial sums (thread = bin, contiguous
// row chunk, plain stores). Blocks [COL_BLOCKS, ...): booster weights +
// weighted-add per-element values (one thread per batch element).
// ---------------------------------------------------------------------------
__global__ __launch_bounds__(NBINS) void mid_kernel(
        const float* __restrict__ outputs,
        const float* __restrict__ add,
        const float* __restrict__ weights,
        float* __restrict__ colpart,    // (COL_BLOCKS * NBINS) in ws
        float* __restrict__ wpart,      // (B) in ws
        float* __restrict__ out,        // [cost, diff, bnorm, booster(B)]
        int col_blocks, int rows_per_block, int K) {
    const int t = threadIdx.x;
    if (blockIdx.x < (unsigned)col_blocks) {
        const size_t r0 = (size_t)blockIdx.x * rows_per_block;
        float local = 0.0f;
        for (int r = 0; r < rows_per_block; ++r)
            local += outputs[(r0 + r) * NBINS + t];
        colpart[(size_t)blockIdx.x * NBINS + t] = local;
    } else {
        const int b = (blockIdx.x - col_blocks) * NBINS + t;
        const float4* ap = (const float4*)(add + (size_t)b * K);
        float sum = 0.0f;
        for (int j = 0; j < K / 4; ++j) {
            float4 a = ap[j];
            sum += (a.x + a.y) + (a.z + a.w);
        }
        out[3 + b] = fmaxf(0.5f, (2.0f - sum / (float)K) * 0.5f);
        wpart[b] = weights[b] * sum;
    }
}

// ---------------------------------------------------------------------------
// Kernel 3: finalize. 512 threads: sum column partials -> min/max reduce;
// parallel-reduce wpart; thread 0 writes the 3 scalars.
// ---------------------------------------------------------------------------
__global__ __launch_bounds__(NBINS) void final_kernel(
        const float* __restrict__ colpart,
        const float* __restrict__ wpart,
        float* __restrict__ out,
        int npart, int B, float inv_count, float inv_target) {
    __shared__ float smax[NBINS];
    __shared__ float smin[NBINS];
    __shared__ float ssum[NBINS];
    const int t = threadIdx.x;

    float v = 0.0f;
    for (int j = 0; j < npart; ++j)
        v += colpart[(size_t)j * NBINS + t];
    smax[t] = v;
    smin[t] = v;

    float wsum = 0.0f;
    for (int i = t; i < B; i += NBINS)
        wsum += wpart[i];
    ssum[t] = wsum;
    __syncthreads();

    for (int s = NBINS / 2; s > 0; s >>= 1) {
        if (t < s) {
            smax[t] = fmaxf(smax[t], smax[t + s]);
            smin[t] = fminf(smin[t], smin[t + s]);
            ssum[t] += ssum[t + s];
        }
        __syncthreads();
    }
    if (t == 0) {
        float add_mean = ssum[0] * inv_count;
        float d = 2.0f - add_mean;
        float diff = d * d;
        float bn = (smax[0] - smin[0]) * inv_target;
        out[0] = bn + diff;
        out[1] = diff;
        out[2] = bn;
    }
}

extern "C" void kernel_launch(void* const* d_in, const int* in_sizes, int n_in,
                              void* d_out, int out_size, void* d_ws, size_t ws_size,
                              hipStream_t stream) {
    const float* outputs = (const float*)d_in[0];  // (N, 512)
    const float* y       = (const float*)d_in[1];  // (B, K)
    const float* weights = (const float*)d_in[2];  // (B,)
    float* out = (float*)d_out;

    const int B = in_sizes[2];              // 8192
    const int K = in_sizes[1] / B;          // 16
    const int N = in_sizes[0] / NBINS;      // 100000

    const int COL_BLOCKS = 256;
    const int rows_per_block = B / COL_BLOCKS;   // 32
    const int BOOST_BLOCKS = B / NBINS;          // 16

    // ws layout (floats): add[B*K] | wpart[B] | colpart[COL_BLOCKS*NBINS]
    float* ws      = (float*)d_ws;
    float* add     = ws;
    float* wpart   = add + (size_t)B * K;
    float* colpart = wpart + B;

    gather_kernel<<<B, BDIM, 0, stream>>>(outputs, y, add, K);
    mid_kernel<<<COL_BLOCKS + BOOST_BLOCKS, NBINS, 0, stream>>>(
        outputs, add, weights, colpart, wpart, out,
        COL_BLOCKS, rows_per_block, K);
    final_kernel<<<1, NBINS, 0, stream>>>(colpart, wpart, out,
                                          COL_BLOCKS, B,
                                          1.0f / (float)(B * K),
                                          (float)NBINS / (float)N);
}